// Round 5
// baseline (725.979 us; speedup 1.0000x reference)
//
#include <hip/hip_runtime.h>
#include <hip/hip_bf16.h>
#include <stdint.h>

#define ENC_B 8192
#define NFED  16384
#define INDIM 1024
#define LAT   512
#define SCALE (1.0f/512.0f)

typedef __attribute__((ext_vector_type(4))) float f32x4;
typedef __attribute__((ext_vector_type(8))) short short8;
typedef __attribute__((ext_vector_type(4))) short short4_t;

// f32 -> bf16, round-to-nearest-even (inputs are finite)
static __device__ __forceinline__ short f2bf(float x){
  union { float f; uint32_t u; } v; v.f = x;
  uint32_t r = v.u + 0x7FFFu + ((v.u >> 16) & 1u);
  return (short)(r >> 16);
}

// async global->LDS, 16B per lane, LDS dest = wave-uniform base + lane*16
static __device__ __forceinline__ void gload16(const void* g, void* l){
  __builtin_amdgcn_global_load_lds(
      (const __attribute__((address_space(1))) void*)g,
      (__attribute__((address_space(3))) void*)l, 16, 0, 0);
}

// counted waits (do NOT drain the async-load queue) + raw barrier
static __device__ __forceinline__ void wait_lgkm0(){ asm volatile("s_waitcnt lgkmcnt(0)" ::: "memory"); }
static __device__ __forceinline__ void wait_vm8(){ asm volatile("s_waitcnt vmcnt(8)" ::: "memory"); }

// ---------------- kernel 1: domain_diff [1024][512] f32 -> ddT [512][1024] bf16 ----
__global__ void ddT_kernel(const float* __restrict__ dd, short* __restrict__ ddT){
  const int n = blockIdx.x;                 // 0..511
  for (int k = threadIdx.x; k < INDIM; k += 256)
    ddT[(size_t)n*INDIM + k] = f2bf(dd[(size_t)k*LAT + n]);
}

// ---------------- kernel 2: kv[16384][512] bf16 = X[16384][1024] @ dd ---------------
__global__ __launch_bounds__(256, 2) void kv_gemm_kernel(const float* __restrict__ X,
                                                         const short* __restrict__ ddT,
                                                         short* __restrict__ kv){
  __shared__ __align__(16) short As[128*40];   // [row][k] bf16, pad->80B rows
  __shared__ __align__(16) short Bs[128*40];   // [col][k] bf16 (from ddT)
  const int t = threadIdx.x;
  const int lane = t & 63, w = t >> 6;
  const int lr = lane & 15, lg = lane >> 4;
  const int m0 = (blockIdx.x >> 2) * 128;
  const int n0 = (blockIdx.x & 3) * 128;
  const int wm = (w >> 1) * 64, wn = (w & 1) * 64;
  f32x4 acc[4][4];
  #pragma unroll
  for (int i=0;i<4;++i)
    #pragma unroll
    for (int j=0;j<4;++j) acc[i][j] = (f32x4){0.f,0.f,0.f,0.f};

  for (int k0 = 0; k0 < INDIM; k0 += 32) {
    #pragma unroll
    for (int i = 0; i < 4; ++i) {               // A: 128x32 f32 -> bf16
      int idx = t + i*256;                       // 1024 float4s
      int row = idx >> 3, c4 = (idx & 7)*4;
      float4 v = *(const float4*)(X + (size_t)(m0+row)*INDIM + k0 + c4);
      short4_t s; s[0]=f2bf(v.x); s[1]=f2bf(v.y); s[2]=f2bf(v.z); s[3]=f2bf(v.w);
      *(short4_t*)(As + row*40 + c4) = s;
    }
    #pragma unroll
    for (int i = 0; i < 2; ++i) {               // B: 128x32 bf16 from ddT
      int idx = t + i*256;                       // 512 uint4s
      int row = idx >> 2, c8 = (idx & 3)*8;
      *(uint4*)(Bs + row*40 + c8) = *(const uint4*)(ddT + (size_t)(n0+row)*INDIM + k0 + c8);
    }
    __syncthreads();
    short8 a[4], b[4];
    #pragma unroll
    for (int i=0;i<4;++i) a[i] = *(short8*)(As + (wm + i*16 + lr)*40 + lg*8);
    #pragma unroll
    for (int i=0;i<4;++i) b[i] = *(short8*)(Bs + (wn + i*16 + lr)*40 + lg*8);
    #pragma unroll
    for (int i=0;i<4;++i)
      #pragma unroll
      for (int j=0;j<4;++j)
        acc[i][j] = __builtin_amdgcn_mfma_f32_16x16x32_bf16(a[i], b[j], acc[i][j], 0,0,0);
    __syncthreads();
  }
  #pragma unroll
  for (int i=0;i<4;++i)
    #pragma unroll
    for (int j=0;j<4;++j)
      #pragma unroll
      for (int r=0;r<4;++r)
        kv[(size_t)(m0 + wm + i*16 + lg*4 + r)*LAT + n0 + wn + j*16 + lr] = f2bf(acc[i][j][r]);
}

// ---------------- kernel 2b: kvT[512][16384] = transpose(kv) ------------------------
__global__ __launch_bounds__(256) void kvT_kernel(const short* __restrict__ kv,
                                                  short* __restrict__ kvT){
  __shared__ short tile[64][72];                 // +8 pad breaks bank alias
  const int t = threadIdx.x;
  const int bn = blockIdx.x & (NFED/64 - 1);     // 256 n-tiles
  const int bd = blockIdx.x / (NFED/64);         // 8 d-tiles
  #pragma unroll
  for (int i=0;i<2;++i){                         // load 64(n) x 64(d)
    int idx = t + i*256; int row = idx >> 3, cc = (idx & 7)*8;
    *(uint4*)&tile[row][cc] = *(const uint4*)(kv + (size_t)(bn*64+row)*LAT + bd*64 + cc);
  }
  __syncthreads();
  #pragma unroll
  for (int i=0;i<2;++i){                         // store 64(d) x 64(n)
    int idx = t + i*256; int drow = idx >> 3, nn = (idx & 7)*8;
    short8 v;
    #pragma unroll
    for (int j=0;j<8;++j) v[j] = tile[nn+j][drow];
    *(short8*)(kvT + (size_t)(bd*64+drow)*NFED + bn*64 + nn) = v;
  }
}

// ---------------- kernel 3: attention, fixed-max softmax, counted-wait pipeline -----
// Per tile: [issue K(t+1)] [QK] [exp+Ps write] [lgkmcnt(0); s_barrier] [PV]
// [issue V(t+1)] [vmcnt(8); s_barrier]  — K/V loads stay in flight across barriers.
__global__ __launch_bounds__(256, 2) void attn_kernel(const float* __restrict__ enc,
                                                      const short* __restrict__ kv,
                                                      const short* __restrict__ kvT,
                                                      float* __restrict__ out,
                                                      float* __restrict__ opart,
                                                      float* __restrict__ ml,
                                                      int nsplit){
  // buf0 32K | buf1 32K | Ps0 2560 | Ps1 2560 | lred 256
  __shared__ __align__(16) char lds[65536 + 5120 + 256];
  short* Ps   = (short*)(lds + 65536);           // 2 x [32][40] bf16
  float* lred = (float*)(lds + 65536 + 5120);    // [2][32]

  const int t = threadIdx.x;
  const int lane = t & 63, w = t >> 6;
  const int lr = lane & 15, lg = lane >> 4;
  const int bx = blockIdx.x;
  const int qt = (nsplit == 2) ? (bx >> 1) : bx;
  const int sp = (nsplit == 2) ? (bx & 1) : 0;
  const int q0 = qt * 32;
  const int nbase = sp * (NFED/2);
  const int nt = NFED / (32*nsplit);
  const int mt = w >> 1, kh = w & 1;

  // Q (wave rows mt*16..+16) into registers, scale folded
  short8 qreg[16];
  {
    const float* qp = enc + (size_t)(q0 + mt*16 + lr)*LAT + lg*8;
    #pragma unroll
    for (int d0 = 0; d0 < 16; ++d0) {
      float4 v0 = *(const float4*)(qp + d0*32);
      float4 v1 = *(const float4*)(qp + d0*32 + 4);
      short8 s;
      s[0]=f2bf(v0.x*SCALE); s[1]=f2bf(v0.y*SCALE); s[2]=f2bf(v0.z*SCALE); s[3]=f2bf(v0.w*SCALE);
      s[4]=f2bf(v1.x*SCALE); s[5]=f2bf(v1.y*SCALE); s[6]=f2bf(v1.z*SCALE); s[7]=f2bf(v1.w*SCALE);
      qreg[d0] = s;
    }
  }

  // K staging: wave w stages rows {w,4+w,..,28+w}; lane chunk l fetches global
  // chunk (l ^ s(row)) so linear LDS + read-side XOR reconstructs.
  uint32_t koff[8];
  #pragma unroll
  for (int i=0;i<8;++i){
    int row = i*4 + w;
    int s = (row ^ (row>>3)) & 7;
    koff[i] = (uint32_t)(nbase + row)*1024u + (uint32_t)((lane ^ s) * 16);
  }

  const int dcol0 = w * 128;                     // PV: wave owns d-slice of 128
  uint32_t vboff[8];                             // byte offsets into kvT
  #pragma unroll
  for (int n=0;n<8;++n)
    vboff[n] = ((uint32_t)(dcol0 + n*16 + lr) * NFED + (uint32_t)(lg*8)) * 2u;

  float lacc[4] = {0.f, 0.f, 0.f, 0.f};
  f32x4 oacc[2][8];
  #pragma unroll
  for (int i=0;i<2;++i)
    #pragma unroll
    for (int n=0;n<8;++n) oacc[i][n] = (f32x4){0.f,0.f,0.f,0.f};

  // ---- prologue: stage K(0) -> buf0, V(0) -> vreg ----
  #pragma unroll
  for (int i=0;i<8;++i){
    gload16((const char*)kv + koff[i], lds + (i*4 + w)*1024);
    koff[i] += 32768u;
  }
  short8 vreg[8];
  #pragma unroll
  for (int n=0;n<8;++n)
    vreg[n] = *(const short8*)((const char*)kvT + vboff[n] + (size_t)nbase*2);
  wait_vm8();                                    // K(0) staged (V(0) may be in flight)
  __builtin_amdgcn_s_barrier();
  __builtin_amdgcn_sched_barrier(0);

  const int key = kh*16 + lr;
  const uint32_t swz = ((uint32_t)((key ^ (key>>3)) & 7)) << 4;

  for (int tt = 0; tt < nt; ++tt) {
    char* bufC = lds + ((tt & 1) << 15);
    char* bufN = lds + (((tt+1) & 1) << 15);
    const bool more = (tt+1 < nt);

    // (1) issue K(t+1) early: full tile of latency hiding before it's needed
    if (more) {
      #pragma unroll
      for (int i=0;i<8;++i){
        gload16((const char*)kv + koff[i], bufN + (i*4 + w)*1024);
        koff[i] += 32768u;
      }
    }

    // (2) QK^T: S[mt-rows][kh-keys] over d=512
    f32x4 sacc = (f32x4){0.f,0.f,0.f,0.f};
    __builtin_amdgcn_s_setprio(1);
    #pragma unroll
    for (int d0 = 0; d0 < 16; ++d0) {
      short8 b = *(short8*)(bufC + (uint32_t)(key*1024) + (uint32_t)((d0*64 + lg*16) ^ swz));
      sacc = __builtin_amdgcn_mfma_f32_16x16x32_bf16(qreg[d0], b, sacc, 0,0,0);
    }
    __builtin_amdgcn_s_setprio(0);

    // (3) P = exp(S); defer row-sum; write P^(bf16) to Ps[t&1]
    short* psW = Ps + (tt & 1)*1280;
    {
      float p0 = __expf(sacc[0]), p1 = __expf(sacc[1]),
            p2 = __expf(sacc[2]), p3 = __expf(sacc[3]);
      lacc[0] += p0; lacc[1] += p1; lacc[2] += p2; lacc[3] += p3;
      const int rowb = mt*16 + lg*4;
      psW[(rowb+0)*40 + key] = f2bf(p0);
      psW[(rowb+1)*40 + key] = f2bf(p1);
      psW[(rowb+2)*40 + key] = f2bf(p2);
      psW[(rowb+3)*40 + key] = f2bf(p3);
    }

    // (4) BAR_B: my ds ops retired, then barrier (async K loads remain in flight)
    wait_lgkm0();
    __builtin_amdgcn_s_barrier();
    __builtin_amdgcn_sched_barrier(0);

    // (5) PV: O[32 x 128-slice] += P(32x32) @ V(32x128-slice), V in regs
    {
      short8 pa0 = *(short8*)(psW + (0  + lr)*40 + lg*8);
      short8 pa1 = *(short8*)(psW + (16 + lr)*40 + lg*8);
      __builtin_amdgcn_s_setprio(1);
      #pragma unroll
      for (int n=0;n<8;++n) {
        oacc[0][n] = __builtin_amdgcn_mfma_f32_16x16x32_bf16(pa0, vreg[n], oacc[0][n], 0,0,0);
        oacc[1][n] = __builtin_amdgcn_mfma_f32_16x16x32_bf16(pa1, vreg[n], oacc[1][n], 0,0,0);
      }
      __builtin_amdgcn_s_setprio(0);
    }

    // (6) issue V(t+1); consumed next tile after BAR_B(t+1)
    if (more) {
      const int n1 = nbase + (tt+1)*32;
      #pragma unroll
      for (int n=0;n<8;++n)
        vreg[n] = *(const short8*)((const char*)kvT + vboff[n] + (size_t)n1*2);
    }

    // (7) BAR_A: my 8 K(t+1) gloads done (8 newer V loads may stay outstanding)
    wait_vm8();
    __builtin_amdgcn_s_barrier();
    __builtin_amdgcn_sched_barrier(0);
  }

  // ---- row-sum reduce: over 16 lr lanes, then across kh waves via LDS ----
  #pragma unroll
  for (int r=0;r<4;++r){
    float v = lacc[r];
    v += __shfl_xor(v, 1, 64); v += __shfl_xor(v, 2, 64);
    v += __shfl_xor(v, 4, 64); v += __shfl_xor(v, 8, 64);
    if (lr == 0) lred[kh*32 + mt*16 + lg*4 + r] = v;
  }
  __syncthreads();

  if (nsplit == 1) {
    #pragma unroll
    for (int i=0;i<2;++i)
      #pragma unroll
      for (int r=0;r<4;++r) {
        int rl = i*16 + lg*4 + r;
        float linv = 1.0f / (lred[rl] + lred[32 + rl]);
        #pragma unroll
        for (int n=0;n<8;++n)
          out[(size_t)(q0 + rl)*LAT + dcol0 + n*16 + lr] = oacc[i][n][r] * linv;
      }
  } else {
    if (t < 32) {
      size_t mi = (size_t)(sp*ENC_B + q0 + t)*2;
      ml[mi] = 0.0f; ml[mi+1] = lred[t] + lred[32 + t];
    }
    #pragma unroll
    for (int i=0;i<2;++i)
      #pragma unroll
      for (int r=0;r<4;++r) {
        size_t row = (size_t)sp*ENC_B + q0 + i*16 + lg*4 + r;
        #pragma unroll
        for (int n=0;n<8;++n)
          opart[row*LAT + dcol0 + n*16 + lr] = oacc[i][n][r];
      }
  }
}

// ---------------- kernel 4: combine of 2 partials (m=0 both) ------------------------
__global__ __launch_bounds__(128) void combine_kernel(const float* __restrict__ opart,
                                                      const float* __restrict__ ml,
                                                      float* __restrict__ out){
  const int row = blockIdx.x;
  const int t = threadIdx.x;                     // 128 thr x float4 = 512
  float m0 = ml[(size_t)row*2],          l0 = ml[(size_t)row*2 + 1];
  float m1 = ml[(size_t)(ENC_B+row)*2],  l1 = ml[(size_t)(ENC_B+row)*2 + 1];
  float m = fmaxf(m0, m1);
  float e0 = __expf(m0 - m), e1 = __expf(m1 - m);
  float inv = 1.0f / (e0*l0 + e1*l1);
  float4 a = *(const float4*)(opart + (size_t)row*LAT + t*4);
  float4 b = *(const float4*)(opart + (size_t)(ENC_B+row)*LAT + t*4);
  float4 r;
  r.x = (e0*a.x + e1*b.x)*inv; r.y = (e0*a.y + e1*b.y)*inv;
  r.z = (e0*a.z + e1*b.z)*inv; r.w = (e0*a.w + e1*b.w)*inv;
  *(float4*)(out + (size_t)row*LAT + t*4) = r;
}

extern "C" void kernel_launch(void* const* d_in, const int* in_sizes, int n_in,
                              void* d_out, int out_size, void* d_ws, size_t ws_size,
                              hipStream_t stream) {
  const float* enc = (const float*)d_in[0];   // 8192 x 512
  const float* X   = (const float*)d_in[1];   // 16384 x 1024
  const float* dd  = (const float*)d_in[2];   // 1024 x 512
  float* out = (float*)d_out;                  // 8192 x 512 f32

  // ws layout: kv 16M | kvT 16M | ddT 1M (dead after gemm) / opart 32M | ml 128K
  short* kvb = (short*)d_ws;                                      // 16,777,216
  short* kvT = (short*)((char*)d_ws + 16777216);                  // 16,777,216
  short* ddT = (short*)((char*)d_ws + 33554432);                  // 1,048,576 (prep only)
  float* opart = (float*)((char*)d_ws + 33554432);                // 32M (attn only)
  float* ml    = (float*)((char*)d_ws + 67108864);                // 128K
  const int nsplit = (ws_size >= (size_t)67239936) ? 2 : 1;

  ddT_kernel<<<LAT, 256, 0, stream>>>(dd, ddT);
  kv_gemm_kernel<<<(NFED/128)*(LAT/128), 256, 0, stream>>>(X, ddT, kvb);
  kvT_kernel<<<(NFED/64)*(LAT/64), 256, 0, stream>>>(kvb, kvT);
  attn_kernel<<<(ENC_B/32)*nsplit, 256, 0, stream>>>(enc, kvb, kvT, out,
                                                     opart, ml, nsplit);
  if (nsplit == 2)
    combine_kernel<<<ENC_B, 128, 0, stream>>>(opart, ml, out);
}

// Round 6
// 532.792 us; speedup vs baseline: 1.3626x; 1.3626x over previous
//
#include <hip/hip_runtime.h>
#include <hip/hip_bf16.h>
#include <stdint.h>

#define ENC_B 8192
#define NFED  16384
#define INDIM 1024
#define LAT   512
#define SCALE (1.0f/512.0f)

typedef __attribute__((ext_vector_type(4))) float f32x4;
typedef __attribute__((ext_vector_type(8))) short short8;
typedef __attribute__((ext_vector_type(4))) short short4_t;

// f32 -> bf16, round-to-nearest-even (inputs are finite)
static __device__ __forceinline__ short f2bf(float x){
  union { float f; uint32_t u; } v; v.f = x;
  uint32_t r = v.u + 0x7FFFu + ((v.u >> 16) & 1u);
  return (short)(r >> 16);
}

// async global->LDS, 16B per lane (flash path)
static __device__ __forceinline__ void gload16(const void* g, void* l){
  __builtin_amdgcn_global_load_lds(
      (const __attribute__((address_space(1))) void*)g,
      (__attribute__((address_space(3))) void*)l, 16, 0, 0);
}

// ---------------- kernel 1: domain_diff [1024][512] f32 -> ddT [512][1024] bf16 ----
__global__ void ddT_kernel(const float* __restrict__ dd, short* __restrict__ ddT){
  const int n = blockIdx.x;                 // 0..511
  for (int k = threadIdx.x; k < INDIM; k += 256)
    ddT[(size_t)n*INDIM + k] = f2bf(dd[(size_t)k*LAT + n]);
}

// ---------------- kernel 1b: enc [8192][512] f32 -> encb bf16 (scale folded) --------
__global__ __launch_bounds__(256) void encb_kernel(const float* __restrict__ enc,
                                                   short* __restrict__ encb){
  const int gid = blockIdx.x*256 + threadIdx.x;   // grid 2048 -> 4M elems, 8 each
  const size_t base = (size_t)gid * 8;
  float4 v0 = *(const float4*)(enc + base);
  float4 v1 = *(const float4*)(enc + base + 4);
  short8 s;
  s[0]=f2bf(v0.x*SCALE); s[1]=f2bf(v0.y*SCALE); s[2]=f2bf(v0.z*SCALE); s[3]=f2bf(v0.w*SCALE);
  s[4]=f2bf(v1.x*SCALE); s[5]=f2bf(v1.y*SCALE); s[6]=f2bf(v1.z*SCALE); s[7]=f2bf(v1.w*SCALE);
  *(short8*)(encb + base) = s;
}

// ---------------- kernel 2: kv[16384][512] bf16 = X[16384][1024] @ dd ---------------
__global__ __launch_bounds__(256, 2) void kv_gemm_kernel(const float* __restrict__ X,
                                                         const short* __restrict__ ddT,
                                                         short* __restrict__ kv){
  __shared__ __align__(16) short As[128*40];
  __shared__ __align__(16) short Bs[128*40];
  const int t = threadIdx.x;
  const int lane = t & 63, w = t >> 6;
  const int lr = lane & 15, lg = lane >> 4;
  const int m0 = (blockIdx.x >> 2) * 128;
  const int n0 = (blockIdx.x & 3) * 128;
  const int wm = (w >> 1) * 64, wn = (w & 1) * 64;
  f32x4 acc[4][4];
  #pragma unroll
  for (int i=0;i<4;++i)
    #pragma unroll
    for (int j=0;j<4;++j) acc[i][j] = (f32x4){0.f,0.f,0.f,0.f};

  for (int k0 = 0; k0 < INDIM; k0 += 32) {
    #pragma unroll
    for (int i = 0; i < 4; ++i) {
      int idx = t + i*256;
      int row = idx >> 3, c4 = (idx & 7)*4;
      float4 v = *(const float4*)(X + (size_t)(m0+row)*INDIM + k0 + c4);
      short4_t s; s[0]=f2bf(v.x); s[1]=f2bf(v.y); s[2]=f2bf(v.z); s[3]=f2bf(v.w);
      *(short4_t*)(As + row*40 + c4) = s;
    }
    #pragma unroll
    for (int i = 0; i < 2; ++i) {
      int idx = t + i*256;
      int row = idx >> 2, c8 = (idx & 3)*8;
      *(uint4*)(Bs + row*40 + c8) = *(const uint4*)(ddT + (size_t)(n0+row)*INDIM + k0 + c8);
    }
    __syncthreads();
    short8 a[4], b[4];
    #pragma unroll
    for (int i=0;i<4;++i) a[i] = *(short8*)(As + (wm + i*16 + lr)*40 + lg*8);
    #pragma unroll
    for (int i=0;i<4;++i) b[i] = *(short8*)(Bs + (wn + i*16 + lr)*40 + lg*8);
    #pragma unroll
    for (int i=0;i<4;++i)
      #pragma unroll
      for (int j=0;j<4;++j)
        acc[i][j] = __builtin_amdgcn_mfma_f32_16x16x32_bf16(a[i], b[j], acc[i][j], 0,0,0);
    __syncthreads();
  }
  #pragma unroll
  for (int i=0;i<4;++i)
    #pragma unroll
    for (int j=0;j<4;++j)
      #pragma unroll
      for (int r=0;r<4;++r)
        kv[(size_t)(m0 + wm + i*16 + lg*4 + r)*LAT + n0 + wn + j*16 + lr] = f2bf(acc[i][j][r]);
}

// ---------------- kernel 2b: kvT[512][16384] = transpose(kv) ------------------------
__global__ __launch_bounds__(256) void kvT_kernel(const short* __restrict__ kv,
                                                  short* __restrict__ kvT){
  __shared__ short tile[64][72];
  const int t = threadIdx.x;
  const int bn = blockIdx.x & (NFED/64 - 1);
  const int bd = blockIdx.x / (NFED/64);
  #pragma unroll
  for (int i=0;i<2;++i){
    int idx = t + i*256; int row = idx >> 3, cc = (idx & 7)*8;
    *(uint4*)&tile[row][cc] = *(const uint4*)(kv + (size_t)(bn*64+row)*LAT + bd*64 + cc);
  }
  __syncthreads();
  #pragma unroll
  for (int i=0;i<2;++i){
    int idx = t + i*256; int drow = idx >> 3, nn = (idx & 7)*8;
    short8 v;
    #pragma unroll
    for (int j=0;j<8;++j) v[j] = tile[nn+j][drow];
    *(short8*)(kvT + (size_t)(bd*64+drow)*NFED + bn*64 + nn) = v;
  }
}

// ---------------- kernel 5: S-chunk GEMM + exp epilogue -----------------------------
// Pc[8192][chunk] bf16 = exp(encb @ kv^T) for keys [cbase, cbase+chunk).
// Also writes per-(128-col-slice) row sums to lpart[slice][8192].
// grid: dim3(chunk/128, 64), 256 thr.
__global__ __launch_bounds__(256, 2) void s_gemm_kernel(const short* __restrict__ encb,
                                                        const short* __restrict__ kv,
                                                        short* __restrict__ Pc,
                                                        float* __restrict__ lpart,
                                                        int cbase, int chunk){
  __shared__ __align__(16) short As[128*40];
  __shared__ __align__(16) short Bs[128*40];
  __shared__ float lsum[128][2];
  const int t = threadIdx.x;
  const int lane = t & 63, w = t >> 6;
  const int lr = lane & 15, lg = lane >> 4;
  const int m0 = blockIdx.y * 128;               // q-rows
  const int n0g = cbase + blockIdx.x * 128;      // global key base
  const int wm = (w >> 1) * 64, wn = (w & 1) * 64;
  f32x4 acc[4][4];
  #pragma unroll
  for (int i=0;i<4;++i)
    #pragma unroll
    for (int j=0;j<4;++j) acc[i][j] = (f32x4){0.f,0.f,0.f,0.f};

  for (int k0 = 0; k0 < LAT; k0 += 32) {
    #pragma unroll
    for (int i = 0; i < 2; ++i) {                // A: 128x32 bf16 from encb
      int idx = t + i*256;
      int row = idx >> 2, c8 = (idx & 3)*8;
      *(uint4*)(As + row*40 + c8) = *(const uint4*)(encb + (size_t)(m0+row)*LAT + k0 + c8);
    }
    #pragma unroll
    for (int i = 0; i < 2; ++i) {                // B: 128x32 bf16 from kv
      int idx = t + i*256;
      int row = idx >> 2, c8 = (idx & 3)*8;
      *(uint4*)(Bs + row*40 + c8) = *(const uint4*)(kv + (size_t)(n0g+row)*LAT + k0 + c8);
    }
    __syncthreads();
    short8 a[4], b[4];
    #pragma unroll
    for (int i=0;i<4;++i) a[i] = *(short8*)(As + (wm + i*16 + lr)*40 + lg*8);
    #pragma unroll
    for (int i=0;i<4;++i) b[i] = *(short8*)(Bs + (wn + i*16 + lr)*40 + lg*8);
    #pragma unroll
    for (int i=0;i<4;++i)
      #pragma unroll
      for (int j=0;j<4;++j)
        acc[i][j] = __builtin_amdgcn_mfma_f32_16x16x32_bf16(a[i], b[j], acc[i][j], 0,0,0);
    __syncthreads();
  }

  // epilogue: p = exp(s); store bf16 to Pc (chunk-local cols); accumulate row sums
  float psum[4][4];                              // [i][r]
  #pragma unroll
  for (int i=0;i<4;++i)
    #pragma unroll
    for (int r=0;r<4;++r) psum[i][r] = 0.f;

  const int collocal0 = blockIdx.x * 128 + wn;
  #pragma unroll
  for (int i=0;i<4;++i)
    #pragma unroll
    for (int j=0;j<4;++j)
      #pragma unroll
      for (int r=0;r<4;++r) {
        float p = __expf(acc[i][j][r]);
        psum[i][r] += p;
        Pc[(size_t)(m0 + wm + i*16 + lg*4 + r)*chunk + collocal0 + j*16 + lr] = f2bf(p);
      }
  #pragma unroll
  for (int i=0;i<4;++i)
    #pragma unroll
    for (int r=0;r<4;++r) {
      float v = psum[i][r];
      v += __shfl_xor(v, 1, 16); v += __shfl_xor(v, 2, 16);
      v += __shfl_xor(v, 4, 16); v += __shfl_xor(v, 8, 16);
      if (lr == 0) lsum[wm + i*16 + lg*4 + r][w & 1] = v;
    }
  __syncthreads();
  if (t < 128) {
    int jsl = (cbase >> 7) + blockIdx.x;         // global 128-col slice index
    lpart[(size_t)jsl*ENC_B + m0 + t] = lsum[t][0] + lsum[t][1];
  }
}

// ---------------- kernel 6: Z-chunk GEMM (transposed out, split-K=2) ----------------
// zpart[s][512 d][8192 rows] (+)= kvT[:, krange] @ Pc[:, krange]^B
// grid: dim3(64 /*row-tiles*/, 4 /*d-tiles*/, 2 /*splitK*/), 256 thr.
__global__ __launch_bounds__(256, 2) void z_gemm_kernel(const short* __restrict__ kvT,
                                                        const short* __restrict__ Pc,
                                                        float* __restrict__ zpart,
                                                        int cbase, int chunk, int first){
  __shared__ __align__(16) short As[128*40];
  __shared__ __align__(16) short Bs[128*40];
  const int t = threadIdx.x;
  const int lane = t & 63, w = t >> 6;
  const int lr = lane & 15, lg = lane >> 4;
  const int n0 = blockIdx.x * 128;               // q-rows
  const int m0 = blockIdx.y * 128;               // d
  const int s  = blockIdx.z;
  const int kl0 = s * (chunk >> 1);              // chunk-local k start
  const int wm = (w >> 1) * 64, wn = (w & 1) * 64;
  f32x4 acc[4][4];
  #pragma unroll
  for (int i=0;i<4;++i)
    #pragma unroll
    for (int j=0;j<4;++j) acc[i][j] = (f32x4){0.f,0.f,0.f,0.f};

  const int ksteps = chunk >> 6;                 // (chunk/2)/32
  for (int ks = 0; ks < ksteps; ++ks) {
    const int k0l = kl0 + ks*32;
    #pragma unroll
    for (int i = 0; i < 2; ++i) {                // A: 128(d) x 32 from kvT
      int idx = t + i*256;
      int row = idx >> 2, c8 = (idx & 3)*8;
      *(uint4*)(As + row*40 + c8) =
        *(const uint4*)(kvT + (size_t)(m0+row)*NFED + cbase + k0l + c8);
    }
    #pragma unroll
    for (int i = 0; i < 2; ++i) {                // B: 128(rows) x 32 from Pc
      int idx = t + i*256;
      int row = idx >> 2, c8 = (idx & 3)*8;
      *(uint4*)(Bs + row*40 + c8) =
        *(const uint4*)(Pc + (size_t)(n0+row)*chunk + k0l + c8);
    }
    __syncthreads();
    short8 a[4], b[4];
    #pragma unroll
    for (int i=0;i<4;++i) a[i] = *(short8*)(As + (wm + i*16 + lr)*40 + lg*8);
    #pragma unroll
    for (int i=0;i<4;++i) b[i] = *(short8*)(Bs + (wn + i*16 + lr)*40 + lg*8);
    #pragma unroll
    for (int i=0;i<4;++i)
      #pragma unroll
      for (int j=0;j<4;++j)
        acc[i][j] = __builtin_amdgcn_mfma_f32_16x16x32_bf16(a[i], b[j], acc[i][j], 0,0,0);
    __syncthreads();
  }

  // epilogue: accumulate into zpart[s][d][row]
  #pragma unroll
  for (int i=0;i<4;++i)
    #pragma unroll
    for (int j=0;j<4;++j)
      #pragma unroll
      for (int r=0;r<4;++r) {
        size_t idx = ((size_t)s*LAT + m0 + wm + i*16 + lg*4 + r)*ENC_B
                   + n0 + wn + j*16 + lr;
        if (first) zpart[idx] = acc[i][j][r];
        else       zpart[idx] += acc[i][j][r];
      }
}

// ---------------- kernel 7: linv[row] = 1 / sum_j lpart[j][row] ---------------------
__global__ __launch_bounds__(256) void lred_kernel(const float* __restrict__ lpart,
                                                   float* __restrict__ linv){
  const int row = blockIdx.x*256 + threadIdx.x;  // grid 32
  float sum = 0.f;
  for (int j = 0; j < NFED/128; ++j)
    sum += lpart[(size_t)j*ENC_B + row];
  linv[row] = 1.0f / sum;
}

// ---------------- kernel 8: out[row][d] = (zp0[d][row]+zp1[d][row]) * linv[row] -----
__global__ __launch_bounds__(256) void zcomb_kernel(const float* __restrict__ zpart,
                                                    const float* __restrict__ linv,
                                                    float* __restrict__ out){
  __shared__ float tile[64][65];
  const int t = threadIdx.x;
  const int bx = blockIdx.x;                     // row-tile 0..127
  const int by = blockIdx.y;                     // d-tile 0..7
  #pragma unroll
  for (int i=0;i<4;++i){
    int idx = t + i*256;                         // 1024 float4s = 64x64
    int dr = idx >> 4, rc = (idx & 15)*4;
    const float* p0 = zpart + (size_t)(by*64+dr)*ENC_B + bx*64 + rc;
    float4 a = *(const float4*)p0;
    float4 b = *(const float4*)(p0 + (size_t)LAT*ENC_B);
    tile[dr][rc+0] = a.x+b.x; tile[dr][rc+1] = a.y+b.y;
    tile[dr][rc+2] = a.z+b.z; tile[dr][rc+3] = a.w+b.w;
  }
  __syncthreads();
  #pragma unroll
  for (int i=0;i<4;++i){
    int idx = t + i*256;
    int rr = idx >> 4, dc = (idx & 15)*4;
    float li = linv[bx*64 + rr];
    float4 o;
    o.x = tile[dc+0][rr]*li; o.y = tile[dc+1][rr]*li;
    o.z = tile[dc+2][rr]*li; o.w = tile[dc+3][rr]*li;
    *(float4*)(out + (size_t)(bx*64+rr)*LAT + by*64 + dc) = o;
  }
}

// ---------------- flash fallback (R4): fixed-max softmax, 1 barrier/tile ------------
__global__ __launch_bounds__(256, 2) void attn_kernel(const float* __restrict__ enc,
                                                      const short* __restrict__ kv,
                                                      const short* __restrict__ kvT,
                                                      float* __restrict__ out,
                                                      float* __restrict__ opart,
                                                      float* __restrict__ ml,
                                                      int nsplit){
  __shared__ __align__(16) char lds[65536 + 5120 + 256];
  short* Ps   = (short*)(lds + 65536);
  float* lred = (float*)(lds + 65536 + 5120);

  const int t = threadIdx.x;
  const int lane = t & 63, w = t >> 6;
  const int lr = lane & 15, lg = lane >> 4;
  const int bx = blockIdx.x;
  const int qt = (nsplit == 2) ? (bx >> 1) : bx;
  const int sp = (nsplit == 2) ? (bx & 1) : 0;
  const int q0 = qt * 32;
  const int nbase = sp * (NFED/2);
  const int nt = NFED / (32*nsplit);
  const int mt = w >> 1, kh = w & 1;

  short8 qreg[16];
  {
    const float* qp = enc + (size_t)(q0 + mt*16 + lr)*LAT + lg*8;
    #pragma unroll
    for (int d0 = 0; d0 < 16; ++d0) {
      float4 v0 = *(const float4*)(qp + d0*32);
      float4 v1 = *(const float4*)(qp + d0*32 + 4);
      short8 s;
      s[0]=f2bf(v0.x*SCALE); s[1]=f2bf(v0.y*SCALE); s[2]=f2bf(v0.z*SCALE); s[3]=f2bf(v0.w*SCALE);
      s[4]=f2bf(v1.x*SCALE); s[5]=f2bf(v1.y*SCALE); s[6]=f2bf(v1.z*SCALE); s[7]=f2bf(v1.w*SCALE);
      qreg[d0] = s;
    }
  }

  uint32_t koff[8];
  #pragma unroll
  for (int i=0;i<8;++i){
    int row = i*4 + w;
    int s = (row ^ (row>>3)) & 7;
    koff[i] = (uint32_t)(nbase + row)*1024u + (uint32_t)((lane ^ s) * 16);
  }

  const int dcol0 = w * 128;
  uint32_t vboff[8];
  #pragma unroll
  for (int n=0;n<8;++n)
    vboff[n] = ((uint32_t)(dcol0 + n*16 + lr) * NFED + (uint32_t)(lg*8)) * 2u;

  float lacc[4] = {0.f, 0.f, 0.f, 0.f};
  f32x4 oacc[2][8];
  #pragma unroll
  for (int i=0;i<2;++i)
    #pragma unroll
    for (int n=0;n<8;++n) oacc[i][n] = (f32x4){0.f,0.f,0.f,0.f};

  #pragma unroll
  for (int i=0;i<8;++i){
    gload16((const char*)kv + koff[i], lds + (i*4 + w)*1024);
    koff[i] += 32768u;
  }
  short8 vreg[8];
  #pragma unroll
  for (int n=0;n<8;++n)
    vreg[n] = *(const short8*)((const char*)kvT + vboff[n] + (size_t)nbase*2);
  __syncthreads();

  const int key = kh*16 + lr;
  const uint32_t swz = ((uint32_t)((key ^ (key>>3)) & 7)) << 4;

  for (int tt = 0; tt < nt; ++tt) {
    char* bufC = lds + ((tt & 1) << 15);
    const bool more = (tt+1 < nt);

    f32x4 sacc = (f32x4){0.f,0.f,0.f,0.f};
    #pragma unroll
    for (int d0 = 0; d0 < 16; ++d0) {
      short8 b = *(short8*)(bufC + (uint32_t)(key*1024) + (uint32_t)((d0*64 + lg*16) ^ swz));
      sacc = __builtin_amdgcn_mfma_f32_16x16x32_bf16(qreg[d0], b, sacc, 0,0,0);
    }

    if (more) {
      char* bufN = lds + (((tt+1) & 1) << 15);
      #pragma unroll
      for (int i=0;i<8;++i){
        gload16((const char*)kv + koff[i], bufN + (i*4 + w)*1024);
        koff[i] += 32768u;
      }
    }

    short* psW = Ps + (tt & 1)*1280;
    {
      float p0 = __expf(sacc[0]), p1 = __expf(sacc[1]),
            p2 = __expf(sacc[2]), p3 = __expf(sacc[3]);
      lacc[0] += p0; lacc[1] += p1; lacc[2] += p2; lacc[3] += p3;
      const int rowb = mt*16 + lg*4;
      psW[(rowb+0)*40 + key] = f2bf(p0);
      psW[(rowb+1)*40 + key] = f2bf(p1);
      psW[(rowb+2)*40 + key] = f2bf(p2);
      psW[(rowb+3)*40 + key] = f2bf(p3);
    }
    __syncthreads();

    {
      short8 pa0 = *(short8*)(psW + (0  + lr)*40 + lg*8);
      short8 pa1 = *(short8*)(psW + (16 + lr)*40 + lg*8);
      #pragma unroll
      for (int n=0;n<8;++n) {
        oacc[0][n] = __builtin_amdgcn_mfma_f32_16x16x32_bf16(pa0, vreg[n], oacc[0][n], 0,0,0);
        oacc[1][n] = __builtin_amdgcn_mfma_f32_16x16x32_bf16(pa1, vreg[n], oacc[1][n], 0,0,0);
      }
    }
    if (more) {
      const int n1 = nbase + (tt+1)*32;
      #pragma unroll
      for (int n=0;n<8;++n)
        vreg[n] = *(const short8*)((const char*)kvT + vboff[n] + (size_t)n1*2);
    }
  }

  #pragma unroll
  for (int r=0;r<4;++r){
    float v = lacc[r];
    v += __shfl_xor(v, 1, 64); v += __shfl_xor(v, 2, 64);
    v += __shfl_xor(v, 4, 64); v += __shfl_xor(v, 8, 64);
    if (lr == 0) lred[kh*32 + mt*16 + lg*4 + r] = v;
  }
  __syncthreads();

  if (nsplit == 1) {
    #pragma unroll
    for (int i=0;i<2;++i)
      #pragma unroll
      for (int r=0;r<4;++r) {
        int rl = i*16 + lg*4 + r;
        float linv = 1.0f / (lred[rl] + lred[32 + rl]);
        #pragma unroll
        for (int n=0;n<8;++n)
          out[(size_t)(q0 + rl)*LAT + dcol0 + n*16 + lr] = oacc[i][n][r] * linv;
      }
  } else {
    if (t < 32) {
      size_t mi = (size_t)(sp*ENC_B + q0 + t)*2;
      ml[mi] = 0.0f; ml[mi+1] = lred[t] + lred[32 + t];
    }
    #pragma unroll
    for (int i=0;i<2;++i)
      #pragma unroll
      for (int r=0;r<4;++r) {
        size_t row = (size_t)sp*ENC_B + q0 + i*16 + lg*4 + r;
        #pragma unroll
        for (int n=0;n<8;++n)
          opart[row*LAT + dcol0 + n*16 + lr] = oacc[i][n][r];
      }
  }
}

__global__ __launch_bounds__(128) void combine_kernel(const float* __restrict__ opart,
                                                      const float* __restrict__ ml,
                                                      float* __restrict__ out){
  const int row = blockIdx.x;
  const int t = threadIdx.x;
  float m0 = ml[(size_t)row*2],          l0 = ml[(size_t)row*2 + 1];
  float m1 = ml[(size_t)(ENC_B+row)*2],  l1 = ml[(size_t)(ENC_B+row)*2 + 1];
  float m = fmaxf(m0, m1);
  float e0 = __expf(m0 - m), e1 = __expf(m1 - m);
  float inv = 1.0f / (e0*l0 + e1*l1);
  float4 a = *(const float4*)(opart + (size_t)row*LAT + t*4);
  float4 b = *(const float4*)(opart + (size_t)(ENC_B+row)*LAT + t*4);
  float4 r;
  r.x = (e0*a.x + e1*b.x)*inv; r.y = (e0*a.y + e1*b.y)*inv;
  r.z = (e0*a.z + e1*b.z)*inv; r.w = (e0*a.w + e1*b.w)*inv;
  *(float4*)(out + (size_t)row*LAT + t*4) = r;
}

extern "C" void kernel_launch(void* const* d_in, const int* in_sizes, int n_in,
                              void* d_out, int out_size, void* d_ws, size_t ws_size,
                              hipStream_t stream) {
  const float* enc = (const float*)d_in[0];   // 8192 x 512
  const float* X   = (const float*)d_in[1];   // 16384 x 1024
  const float* dd  = (const float*)d_in[2];   // 1024 x 512
  float* out = (float*)d_out;                  // 8192 x 512 f32

  // shared layout: kv 0..16M | kvT 16..32M | ddT 32M+1.5M area (dead after kv_gemm)
  short* kvb = (short*)d_ws;                                      // 16,777,216 B
  short* kvT = (short*)((char*)d_ws + 16777216);                  // 16,777,216 B
  short* ddT = (short*)((char*)d_ws + 33554432);                  // 1 MB, prep only

  // GEMM path extras (zpart overlays the dead ddT region)
  float* zpart = (float*)((char*)d_ws + 33554432);                // 32 MB
  short* encb  = (short*)((char*)d_ws + 67108864);                // 8 MB
  float* lpart = (float*)((char*)d_ws + 75497472);                // 4 MB
  float* linv  = (float*)((char*)d_ws + 79691776);                // 32 KB
  short* Pc    = (short*)((char*)d_ws + 83886080);                // chunk*8192*2 B

  // flash-path extras
  float* opart = (float*)((char*)d_ws + 33554432);                // 32 MB
  float* ml    = (float*)((char*)d_ws + 67108864);                // 128 KB

  int chunk = 0;
  if      (ws_size >= (size_t)83886080 + (size_t)4096*ENC_B*2) chunk = 4096; // 151.0 MB
  else if (ws_size >= (size_t)83886080 + (size_t)2048*ENC_B*2) chunk = 2048; // 117.4 MB
  else if (ws_size >= (size_t)83886080 + (size_t)1024*ENC_B*2) chunk = 1024; // 100.7 MB

  ddT_kernel<<<LAT, 256, 0, stream>>>(dd, ddT);
  kv_gemm_kernel<<<(NFED/128)*(LAT/128), 256, 0, stream>>>(X, ddT, kvb);
  kvT_kernel<<<(NFED/64)*(LAT/64), 256, 0, stream>>>(kvb, kvT);

  if (chunk) {
    encb_kernel<<<ENC_B*LAT/(256*8), 256, 0, stream>>>(enc, encb);
    const int nc = NFED / chunk;
    for (int c = 0; c < nc; ++c) {
      s_gemm_kernel<<<dim3(chunk/128, ENC_B/128), 256, 0, stream>>>(
          encb, kvb, Pc, lpart, c*chunk, chunk);
      z_gemm_kernel<<<dim3(ENC_B/128, LAT/128, 2), 256, 0, stream>>>(
          kvT, Pc, zpart, c*chunk, chunk, (c == 0) ? 1 : 0);
    }
    lred_kernel<<<ENC_B/256, 256, 0, stream>>>(lpart, linv);
    zcomb_kernel<<<dim3(ENC_B/64, LAT/64), 256, 0, stream>>>(zpart, linv, out);
  } else {
    const int nsplit = (ws_size >= (size_t)67239936) ? 2 : 1;
    attn_kernel<<<(ENC_B/32)*nsplit, 256, 0, stream>>>(enc, kvb, kvT, out,
                                                       opart, ml, nsplit);
    if (nsplit == 2)
      combine_kernel<<<ENC_B, 128, 0, stream>>>(opart, ml, out);
  }
}

// Round 7
// 503.720 us; speedup vs baseline: 1.4412x; 1.0577x over previous
//
#include <hip/hip_runtime.h>
#include <hip/hip_bf16.h>
#include <stdint.h>

#define ENC_B 8192
#define NFED  16384
#define INDIM 1024
#define LAT   512
#define SCALE (1.0f/512.0f)

typedef __attribute__((ext_vector_type(4))) float f32x4;
typedef __attribute__((ext_vector_type(8))) short short8;
typedef __attribute__((ext_vector_type(4))) short short4_t;

// f32 -> bf16, round-to-nearest-even (inputs are finite)
static __device__ __forceinline__ short f2bf(float x){
  union { float f; uint32_t u; } v; v.f = x;
  uint32_t r = v.u + 0x7FFFu + ((v.u >> 16) & 1u);
  return (short)(r >> 16);
}

// async global->LDS, 16B per lane; LDS dest = wave-uniform base + lane*16
static __device__ __forceinline__ void gload16(const void* g, void* l){
  __builtin_amdgcn_global_load_lds(
      (const __attribute__((address_space(1))) void*)g,
      (__attribute__((address_space(3))) void*)l, 16, 0, 0);
}

// ---------------- kernel 1: domain_diff [1024][512] f32 -> ddT [512][1024] bf16 ----
__global__ void ddT_kernel(const float* __restrict__ dd, short* __restrict__ ddT){
  const int n = blockIdx.x;                 // 0..511
  for (int k = threadIdx.x; k < INDIM; k += 256)
    ddT[(size_t)n*INDIM + k] = f2bf(dd[(size_t)k*LAT + n]);
}

// ---------------- kernel 1b: enc [8192][512] f32 -> encb bf16 (scale folded) --------
__global__ __launch_bounds__(256) void encb_kernel(const float* __restrict__ enc,
                                                   short* __restrict__ encb){
  const int gid = blockIdx.x*256 + threadIdx.x;   // grid 2048 -> 4M elems, 8 each
  const size_t base = (size_t)gid * 8;
  float4 v0 = *(const float4*)(enc + base);
  float4 v1 = *(const float4*)(enc + base + 4);
  short8 s;
  s[0]=f2bf(v0.x*SCALE); s[1]=f2bf(v0.y*SCALE); s[2]=f2bf(v0.z*SCALE); s[3]=f2bf(v0.w*SCALE);
  s[4]=f2bf(v1.x*SCALE); s[5]=f2bf(v1.y*SCALE); s[6]=f2bf(v1.z*SCALE); s[7]=f2bf(v1.w*SCALE);
  *(short8*)(encb + base) = s;
}

// ---------------- kernel 2: kv[16384][512] bf16 = X[16384][1024] @ dd ---------------
__global__ __launch_bounds__(256, 2) void kv_gemm_kernel(const float* __restrict__ X,
                                                         const short* __restrict__ ddT,
                                                         short* __restrict__ kv){
  __shared__ __align__(16) short As[128*40];
  __shared__ __align__(16) short Bs[128*40];
  const int t = threadIdx.x;
  const int lane = t & 63, w = t >> 6;
  const int lr = lane & 15, lg = lane >> 4;
  const int m0 = (blockIdx.x >> 2) * 128;
  const int n0 = (blockIdx.x & 3) * 128;
  const int wm = (w >> 1) * 64, wn = (w & 1) * 64;
  f32x4 acc[4][4];
  #pragma unroll
  for (int i=0;i<4;++i)
    #pragma unroll
    for (int j=0;j<4;++j) acc[i][j] = (f32x4){0.f,0.f,0.f,0.f};

  for (int k0 = 0; k0 < INDIM; k0 += 32) {
    #pragma unroll
    for (int i = 0; i < 4; ++i) {
      int idx = t + i*256;
      int row = idx >> 3, c4 = (idx & 7)*4;
      float4 v = *(const float4*)(X + (size_t)(m0+row)*INDIM + k0 + c4);
      short4_t s; s[0]=f2bf(v.x); s[1]=f2bf(v.y); s[2]=f2bf(v.z); s[3]=f2bf(v.w);
      *(short4_t*)(As + row*40 + c4) = s;
    }
    #pragma unroll
    for (int i = 0; i < 2; ++i) {
      int idx = t + i*256;
      int row = idx >> 2, c8 = (idx & 3)*8;
      *(uint4*)(Bs + row*40 + c8) = *(const uint4*)(ddT + (size_t)(n0+row)*INDIM + k0 + c8);
    }
    __syncthreads();
    short8 a[4], b[4];
    #pragma unroll
    for (int i=0;i<4;++i) a[i] = *(short8*)(As + (wm + i*16 + lr)*40 + lg*8);
    #pragma unroll
    for (int i=0;i<4;++i) b[i] = *(short8*)(Bs + (wn + i*16 + lr)*40 + lg*8);
    #pragma unroll
    for (int i=0;i<4;++i)
      #pragma unroll
      for (int j=0;j<4;++j)
        acc[i][j] = __builtin_amdgcn_mfma_f32_16x16x32_bf16(a[i], b[j], acc[i][j], 0,0,0);
    __syncthreads();
  }
  #pragma unroll
  for (int i=0;i<4;++i)
    #pragma unroll
    for (int j=0;j<4;++j)
      #pragma unroll
      for (int r=0;r<4;++r)
        kv[(size_t)(m0 + wm + i*16 + lg*4 + r)*LAT + n0 + wn + j*16 + lr] = f2bf(acc[i][j][r]);
}

// ---------------- kernel 2b: kvT[512][16384] = transpose(kv) ------------------------
__global__ __launch_bounds__(256) void kvT_kernel(const short* __restrict__ kv,
                                                  short* __restrict__ kvT){
  __shared__ short tile[64][72];
  const int t = threadIdx.x;
  const int bn = blockIdx.x & (NFED/64 - 1);
  const int bd = blockIdx.x / (NFED/64);
  #pragma unroll
  for (int i=0;i<2;++i){
    int idx = t + i*256; int row = idx >> 3, cc = (idx & 7)*8;
    *(uint4*)&tile[row][cc] = *(const uint4*)(kv + (size_t)(bn*64+row)*LAT + bd*64 + cc);
  }
  __syncthreads();
  #pragma unroll
  for (int i=0;i<2;++i){
    int idx = t + i*256; int drow = idx >> 3, nn = (idx & 7)*8;
    short8 v;
    #pragma unroll
    for (int j=0;j<8;++j) v[j] = tile[nn+j][drow];
    *(short8*)(kvT + (size_t)(bd*64+drow)*NFED + bn*64 + nn) = v;
  }
}

// ---------------- kernel 5: S-chunk GEMM + exp epilogue (gload_lds staging) ---------
// Pc[8192][chunk] bf16 = exp(encb @ kv^T) for keys [cbase, cbase+chunk).
// Per-128-col-slice row sums -> lpart[slice][8192]. grid dim3(chunk/128, 64), 256thr.
__global__ __launch_bounds__(256, 4) void s_gemm_kernel(const short* __restrict__ encb,
                                                        const short* __restrict__ kv,
                                                        short* __restrict__ Pc,
                                                        float* __restrict__ lpart,
                                                        int cbase, int chunk){
  __shared__ __align__(16) short As[128*32];     // 8 KB linear [row][k]
  __shared__ __align__(16) short Bs[128*32];
  __shared__ float lsum[128][2];
  const int t = threadIdx.x;
  const int lane = t & 63, w = t >> 6;
  const int lr = lane & 15, lg = lane >> 4;
  const int m0 = blockIdx.y * 128;               // q-rows
  const int n0g = cbase + blockIdx.x * 128;      // global key base
  const int wm = (w >> 1) * 64, wn = (w & 1) * 64;

  // staging: op j covers rows (j*4+w)*16 + (lane>>2), 16B chunk (lane&3)
  const int sr = lane >> 2, sc = (lane & 3) * 8; // shorts
  const char* Asrc0 = (const char*)(encb + (size_t)(m0 + w*16      + sr)*LAT + sc);
  const char* Asrc1 = (const char*)(encb + (size_t)(m0 + (4+w)*16  + sr)*LAT + sc);
  const char* Bsrc0 = (const char*)(kv   + (size_t)(n0g + w*16     + sr)*LAT + sc);
  const char* Bsrc1 = (const char*)(kv   + (size_t)(n0g + (4+w)*16 + sr)*LAT + sc);
  char* AsD0 = (char*)As + w*1024;  char* AsD1 = (char*)As + (4+w)*1024;
  char* BsD0 = (char*)Bs + w*1024;  char* BsD1 = (char*)Bs + (4+w)*1024;

  f32x4 acc[4][4];
  #pragma unroll
  for (int i=0;i<4;++i)
    #pragma unroll
    for (int j=0;j<4;++j) acc[i][j] = (f32x4){0.f,0.f,0.f,0.f};

  for (int k0 = 0; k0 < LAT; k0 += 32) {
    gload16(Asrc0, AsD0); gload16(Asrc1, AsD1);
    gload16(Bsrc0, BsD0); gload16(Bsrc1, BsD1);
    Asrc0 += 64; Asrc1 += 64; Bsrc0 += 64; Bsrc1 += 64;
    __syncthreads();                             // drains vmcnt: tiles ready
    short8 a[4], b[4];
    #pragma unroll
    for (int i=0;i<4;++i) a[i] = *(short8*)((char*)As + (wm + i*16 + lr)*64 + lg*16);
    #pragma unroll
    for (int i=0;i<4;++i) b[i] = *(short8*)((char*)Bs + (wn + i*16 + lr)*64 + lg*16);
    #pragma unroll
    for (int i=0;i<4;++i)
      #pragma unroll
      for (int j=0;j<4;++j)
        acc[i][j] = __builtin_amdgcn_mfma_f32_16x16x32_bf16(a[i], b[j], acc[i][j], 0,0,0);
    __syncthreads();                             // LDS consumed; safe to restage
  }

  // epilogue: p = exp(s); store bf16 to Pc; accumulate row sums
  float psum[4][4];
  #pragma unroll
  for (int i=0;i<4;++i)
    #pragma unroll
    for (int r=0;r<4;++r) psum[i][r] = 0.f;

  const int collocal0 = blockIdx.x * 128 + wn;
  #pragma unroll
  for (int i=0;i<4;++i)
    #pragma unroll
    for (int j=0;j<4;++j)
      #pragma unroll
      for (int r=0;r<4;++r) {
        float p = __expf(acc[i][j][r]);
        psum[i][r] += p;
        Pc[(size_t)(m0 + wm + i*16 + lg*4 + r)*chunk + collocal0 + j*16 + lr] = f2bf(p);
      }
  #pragma unroll
  for (int i=0;i<4;++i)
    #pragma unroll
    for (int r=0;r<4;++r) {
      float v = psum[i][r];
      v += __shfl_xor(v, 1, 16); v += __shfl_xor(v, 2, 16);
      v += __shfl_xor(v, 4, 16); v += __shfl_xor(v, 8, 16);
      if (lr == 0) lsum[wm + i*16 + lg*4 + r][w & 1] = v;
    }
  __syncthreads();
  if (t < 128) {
    int jsl = (cbase >> 7) + blockIdx.x;         // global 128-col slice index
    lpart[(size_t)jsl*ENC_B + m0 + t] = lsum[t][0] + lsum[t][1];
  }
}

// ---------------- kernel 6: Z-chunk GEMM, gload_lds staging, split-K=4 --------------
// zpart[s][512 d][8192 rows] (+)= kvT[:, krange_s] @ Pc-slice.
// grid dim3(64 row-tiles, 4 d-tiles, 4 splitK), 256 thr.
__global__ __launch_bounds__(256, 4) void z_gemm_kernel(const short* __restrict__ kvT,
                                                        const short* __restrict__ Pc,
                                                        float* __restrict__ zpart,
                                                        int cbase, int chunk, int first){
  __shared__ __align__(16) short As[128*32];
  __shared__ __align__(16) short Bs[128*32];
  const int t = threadIdx.x;
  const int lane = t & 63, w = t >> 6;
  const int lr = lane & 15, lg = lane >> 4;
  const int n0 = blockIdx.x * 128;               // q-rows
  const int m0 = blockIdx.y * 128;               // d
  const int s  = blockIdx.z;
  const int klocal0 = s * (chunk >> 2);          // chunk-local k start
  const int wm = (w >> 1) * 64, wn = (w & 1) * 64;

  const int sr = lane >> 2, sc = (lane & 3) * 8;
  const char* Asrc0 = (const char*)(kvT + (size_t)(m0 + w*16      + sr)*NFED + cbase + klocal0 + sc);
  const char* Asrc1 = (const char*)(kvT + (size_t)(m0 + (4+w)*16  + sr)*NFED + cbase + klocal0 + sc);
  const char* Bsrc0 = (const char*)(Pc  + (size_t)(n0 + w*16      + sr)*chunk + klocal0 + sc);
  const char* Bsrc1 = (const char*)(Pc  + (size_t)(n0 + (4+w)*16  + sr)*chunk + klocal0 + sc);
  char* AsD0 = (char*)As + w*1024;  char* AsD1 = (char*)As + (4+w)*1024;
  char* BsD0 = (char*)Bs + w*1024;  char* BsD1 = (char*)Bs + (4+w)*1024;

  f32x4 acc[4][4];
  #pragma unroll
  for (int i=0;i<4;++i)
    #pragma unroll
    for (int j=0;j<4;++j) acc[i][j] = (f32x4){0.f,0.f,0.f,0.f};

  const int ksteps = chunk >> 7;                 // (chunk/4)/32
  for (int ks = 0; ks < ksteps; ++ks) {
    gload16(Asrc0, AsD0); gload16(Asrc1, AsD1);
    gload16(Bsrc0, BsD0); gload16(Bsrc1, BsD1);
    Asrc0 += 64; Asrc1 += 64; Bsrc0 += 64; Bsrc1 += 64;
    __syncthreads();
    short8 a[4], b[4];
    #pragma unroll
    for (int i=0;i<4;++i) a[i] = *(short8*)((char*)As + (wm + i*16 + lr)*64 + lg*16);
    #pragma unroll
    for (int i=0;i<4;++i) b[i] = *(short8*)((char*)Bs + (wn + i*16 + lr)*64 + lg*16);
    #pragma unroll
    for (int i=0;i<4;++i)
      #pragma unroll
      for (int j=0;j<4;++j)
        acc[i][j] = __builtin_amdgcn_mfma_f32_16x16x32_bf16(a[i], b[j], acc[i][j], 0,0,0);
    __syncthreads();
  }

  // epilogue: accumulate into zpart[s][d][row]
  #pragma unroll
  for (int i=0;i<4;++i)
    #pragma unroll
    for (int j=0;j<4;++j)
      #pragma unroll
      for (int r=0;r<4;++r) {
        size_t idx = ((size_t)s*LAT + m0 + wm + i*16 + lg*4 + r)*ENC_B
                   + n0 + wn + j*16 + lr;
        if (first) zpart[idx] = acc[i][j][r];
        else       zpart[idx] += acc[i][j][r];
      }
}

// ---------------- kernel 7: linv[row] = 1 / sum_j lpart[j][row] ---------------------
__global__ __launch_bounds__(256) void lred_kernel(const float* __restrict__ lpart,
                                                   float* __restrict__ linv){
  const int row = blockIdx.x*256 + threadIdx.x;  // grid 32
  float sum = 0.f;
  for (int j = 0; j < NFED/128; ++j)
    sum += lpart[(size_t)j*ENC_B + row];
  linv[row] = 1.0f / sum;
}

// ---------------- kernel 8: out[row][d] = (sum_s zpart[s][d][row]) * linv[row] ------
__global__ __launch_bounds__(256) void zcomb_kernel(const float* __restrict__ zpart,
                                                    const float* __restrict__ linv,
                                                    float* __restrict__ out){
  __shared__ float tile[64][65];
  const int t = threadIdx.x;
  const int bx = blockIdx.x;                     // row-tile 0..127
  const int by = blockIdx.y;                     // d-tile 0..7
  const size_t sstr = (size_t)LAT*ENC_B;
  #pragma unroll
  for (int i=0;i<4;++i){
    int idx = t + i*256;                         // 1024 float4s = 64x64
    int dr = idx >> 4, rc = (idx & 15)*4;
    const float* p0 = zpart + (size_t)(by*64+dr)*ENC_B + bx*64 + rc;
    float4 a = *(const float4*)p0;
    float4 b = *(const float4*)(p0 + sstr);
    float4 c = *(const float4*)(p0 + 2*sstr);
    float4 d = *(const float4*)(p0 + 3*sstr);
    tile[dr][rc+0] = (a.x+b.x)+(c.x+d.x); tile[dr][rc+1] = (a.y+b.y)+(c.y+d.y);
    tile[dr][rc+2] = (a.z+b.z)+(c.z+d.z); tile[dr][rc+3] = (a.w+b.w)+(c.w+d.w);
  }
  __syncthreads();
  #pragma unroll
  for (int i=0;i<4;++i){
    int idx = t + i*256;
    int rr = idx >> 4, dc = (idx & 15)*4;
    float li = linv[bx*64 + rr];
    float4 o;
    o.x = tile[dc+0][rr]*li; o.y = tile[dc+1][rr]*li;
    o.z = tile[dc+2][rr]*li; o.w = tile[dc+3][rr]*li;
    *(float4*)(out + (size_t)(bx*64+rr)*LAT + by*64 + dc) = o;
  }
}

extern "C" void kernel_launch(void* const* d_in, const int* in_sizes, int n_in,
                              void* d_out, int out_size, void* d_ws, size_t ws_size,
                              hipStream_t stream) {
  const float* enc = (const float*)d_in[0];   // 8192 x 512
  const float* X   = (const float*)d_in[1];   // 16384 x 1024
  const float* dd  = (const float*)d_in[2];   // 1024 x 512
  float* out = (float*)d_out;                  // 8192 x 512 f32

  // ws layout (bytes):
  //   kv    @ 0          16,777,216
  //   kvT   @ 16,777,216 16,777,216
  //   encb  @ 33,554,432  8,388,608
  //   lpart @ 41,943,040  4,194,304   (ddT overlays this region, dead before lpart use)
  //   linv  @ 46,137,344     32,768
  //   zpart @ 50,331,648 67,108,864   (4 slices x 16 MB f32)
  //   Pc    @117,440,512 chunk*16384
  short* kvb   = (short*)d_ws;
  short* kvT   = (short*)((char*)d_ws + 16777216);
  short* encb  = (short*)((char*)d_ws + 33554432);
  float* lpart = (float*)((char*)d_ws + 41943040);
  short* ddT   = (short*)((char*)d_ws + 41943040);   // prep only
  float* linv  = (float*)((char*)d_ws + 46137344);
  float* zpart = (float*)((char*)d_ws + 50331648);
  short* Pc    = (short*)((char*)d_ws + 117440512);

  // tier: ws >= 184,549,376 -> chunk 4096; >= 150,994,944 (proven) -> 2048; else 1024
  int chunk;
  if      (ws_size >= (size_t)117440512 + (size_t)4096*ENC_B*2) chunk = 4096;
  else if (ws_size >= (size_t)117440512 + (size_t)2048*ENC_B*2) chunk = 2048;
  else                                                          chunk = 1024;

  ddT_kernel<<<LAT, 256, 0, stream>>>(dd, ddT);
  kv_gemm_kernel<<<(NFED/128)*(LAT/128), 256, 0, stream>>>(X, ddT, kvb);
  kvT_kernel<<<(NFED/64)*(LAT/64), 256, 0, stream>>>(kvb, kvT);
  encb_kernel<<<ENC_B*LAT/(256*8), 256, 0, stream>>>(enc, encb);

  const int nc = NFED / chunk;
  for (int c = 0; c < nc; ++c) {
    s_gemm_kernel<<<dim3(chunk/128, ENC_B/128), 256, 0, stream>>>(
        encb, kvb, Pc, lpart, c*chunk, chunk);
    z_gemm_kernel<<<dim3(ENC_B/128, LAT/128, 4), 256, 0, stream>>>(
        kvT, Pc, zpart, c*chunk, chunk, (c == 0) ? 1 : 0);
  }
  lred_kernel<<<ENC_B/256, 256, 0, stream>>>(lpart, linv);
  zcomb_kernel<<<dim3(ENC_B/64, LAT/64), 256, 0, stream>>>(zpart, linv, out);
}

// Round 8
// 435.755 us; speedup vs baseline: 1.6660x; 1.1560x over previous
//
#include <hip/hip_runtime.h>
#include <hip/hip_bf16.h>
#include <stdint.h>

#define ENC_B 8192
#define NFED  16384
#define INDIM 1024
#define LAT   512
#define SCALE (1.0f/512.0f)

typedef __attribute__((ext_vector_type(4))) float f32x4;
typedef __attribute__((ext_vector_type(8))) short short8;
typedef __attribute__((ext_vector_type(4))) short short4_t;

// f32 -> bf16, round-to-nearest-even (inputs are finite)
static __device__ __forceinline__ short f2bf(float x){
  union { float f; uint32_t u; } v; v.f = x;
  uint32_t r = v.u + 0x7FFFu + ((v.u >> 16) & 1u);
  return (short)(r >> 16);
}
static __device__ __forceinline__ float bf2f(short s){
  union { float f; uint32_t u; } v; v.u = ((uint32_t)(unsigned short)s) << 16; return v.f;
}

// async global->LDS, 16B per lane; LDS dest = wave-uniform base + lane*16
static __device__ __forceinline__ void gload16(const void* g, void* l){
  __builtin_amdgcn_global_load_lds(
      (const __attribute__((address_space(1))) void*)g,
      (__attribute__((address_space(3))) void*)l, 16, 0, 0);
}

// ---------------- kernel 1: domain_diff [1024][512] f32 -> ddT [512][1024] bf16 ----
__global__ void ddT_kernel(const float* __restrict__ dd, short* __restrict__ ddT){
  const int n = blockIdx.x;                 // 0..511
  for (int k = threadIdx.x; k < INDIM; k += 256)
    ddT[(size_t)n*INDIM + k] = f2bf(dd[(size_t)k*LAT + n]);
}

// ---------------- kernel 1b: enc [8192][512] f32 -> encb bf16 (scale folded) --------
__global__ __launch_bounds__(256) void encb_kernel(const float* __restrict__ enc,
                                                   short* __restrict__ encb){
  const int gid = blockIdx.x*256 + threadIdx.x;   // grid 2048 -> 4M elems, 8 each
  const size_t base = (size_t)gid * 8;
  float4 v0 = *(const float4*)(enc + base);
  float4 v1 = *(const float4*)(enc + base + 4);
  short8 s;
  s[0]=f2bf(v0.x*SCALE); s[1]=f2bf(v0.y*SCALE); s[2]=f2bf(v0.z*SCALE); s[3]=f2bf(v0.w*SCALE);
  s[4]=f2bf(v1.x*SCALE); s[5]=f2bf(v1.y*SCALE); s[6]=f2bf(v1.z*SCALE); s[7]=f2bf(v1.w*SCALE);
  *(short8*)(encb + base) = s;
}

// ---------------- kernel 2: kv[16384][512] bf16 = X[16384][1024] @ dd ---------------
__global__ __launch_bounds__(256, 2) void kv_gemm_kernel(const float* __restrict__ X,
                                                         const short* __restrict__ ddT,
                                                         short* __restrict__ kv){
  __shared__ __align__(16) short As[128*40];
  __shared__ __align__(16) short Bs[128*40];
  const int t = threadIdx.x;
  const int lane = t & 63, w = t >> 6;
  const int lr = lane & 15, lg = lane >> 4;
  const int m0 = (blockIdx.x >> 2) * 128;
  const int n0 = (blockIdx.x & 3) * 128;
  const int wm = (w >> 1) * 64, wn = (w & 1) * 64;
  f32x4 acc[4][4];
  #pragma unroll
  for (int i=0;i<4;++i)
    #pragma unroll
    for (int j=0;j<4;++j) acc[i][j] = (f32x4){0.f,0.f,0.f,0.f};

  for (int k0 = 0; k0 < INDIM; k0 += 32) {
    #pragma unroll
    for (int i = 0; i < 4; ++i) {
      int idx = t + i*256;
      int row = idx >> 3, c4 = (idx & 7)*4;
      float4 v = *(const float4*)(X + (size_t)(m0+row)*INDIM + k0 + c4);
      short4_t s; s[0]=f2bf(v.x); s[1]=f2bf(v.y); s[2]=f2bf(v.z); s[3]=f2bf(v.w);
      *(short4_t*)(As + row*40 + c4) = s;
    }
    #pragma unroll
    for (int i = 0; i < 2; ++i) {
      int idx = t + i*256;
      int row = idx >> 2, c8 = (idx & 3)*8;
      *(uint4*)(Bs + row*40 + c8) = *(const uint4*)(ddT + (size_t)(n0+row)*INDIM + k0 + c8);
    }
    __syncthreads();
    short8 a[4], b[4];
    #pragma unroll
    for (int i=0;i<4;++i) a[i] = *(short8*)(As + (wm + i*16 + lr)*40 + lg*8);
    #pragma unroll
    for (int i=0;i<4;++i) b[i] = *(short8*)(Bs + (wn + i*16 + lr)*40 + lg*8);
    #pragma unroll
    for (int i=0;i<4;++i)
      #pragma unroll
      for (int j=0;j<4;++j)
        acc[i][j] = __builtin_amdgcn_mfma_f32_16x16x32_bf16(a[i], b[j], acc[i][j], 0,0,0);
    __syncthreads();
  }
  #pragma unroll
  for (int i=0;i<4;++i)
    #pragma unroll
    for (int j=0;j<4;++j)
      #pragma unroll
      for (int r=0;r<4;++r)
        kv[(size_t)(m0 + wm + i*16 + lg*4 + r)*LAT + n0 + wn + j*16 + lr] = f2bf(acc[i][j][r]);
}

// ---------------- kernel 2b: kvT[512][16384] = transpose(kv) ------------------------
__global__ __launch_bounds__(256) void kvT_kernel(const short* __restrict__ kv,
                                                  short* __restrict__ kvT){
  __shared__ short tile[64][72];
  const int t = threadIdx.x;
  const int bn = blockIdx.x & (NFED/64 - 1);
  const int bd = blockIdx.x / (NFED/64);
  #pragma unroll
  for (int i=0;i<2;++i){
    int idx = t + i*256; int row = idx >> 3, cc = (idx & 7)*8;
    *(uint4*)&tile[row][cc] = *(const uint4*)(kv + (size_t)(bn*64+row)*LAT + bd*64 + cc);
  }
  __syncthreads();
  #pragma unroll
  for (int i=0;i<2;++i){
    int idx = t + i*256; int drow = idx >> 3, nn = (idx & 7)*8;
    short8 v;
    #pragma unroll
    for (int j=0;j<8;++j) v[j] = tile[nn+j][drow];
    *(short8*)(kvT + (size_t)(bd*64+drow)*NFED + bn*64 + nn) = v;
  }
}

// ---------------- kernel 5: S-chunk GEMM + exp epilogue (gload_lds staging) ---------
// Pc[8192][chunk] bf16 = exp(encb @ kv^T) for keys [cbase, cbase+chunk).
// Per-128-col-slice row sums -> lpart[slice][8192]. grid dim3(chunk/128, 64), 256thr.
__global__ __launch_bounds__(256, 4) void s_gemm_kernel(const short* __restrict__ encb,
                                                        const short* __restrict__ kv,
                                                        short* __restrict__ Pc,
                                                        float* __restrict__ lpart,
                                                        int cbase, int chunk){
  __shared__ __align__(16) short As[128*32];     // 8 KB linear [row][k]
  __shared__ __align__(16) short Bs[128*32];
  __shared__ float lsum[128][2];
  const int t = threadIdx.x;
  const int lane = t & 63, w = t >> 6;
  const int lr = lane & 15, lg = lane >> 4;
  const int m0 = blockIdx.y * 128;               // q-rows
  const int n0g = cbase + blockIdx.x * 128;      // global key base
  const int wm = (w >> 1) * 64, wn = (w & 1) * 64;

  const int sr = lane >> 2, sc = (lane & 3) * 8; // shorts
  const char* Asrc0 = (const char*)(encb + (size_t)(m0 + w*16      + sr)*LAT + sc);
  const char* Asrc1 = (const char*)(encb + (size_t)(m0 + (4+w)*16  + sr)*LAT + sc);
  const char* Bsrc0 = (const char*)(kv   + (size_t)(n0g + w*16     + sr)*LAT + sc);
  const char* Bsrc1 = (const char*)(kv   + (size_t)(n0g + (4+w)*16 + sr)*LAT + sc);
  char* AsD0 = (char*)As + w*1024;  char* AsD1 = (char*)As + (4+w)*1024;
  char* BsD0 = (char*)Bs + w*1024;  char* BsD1 = (char*)Bs + (4+w)*1024;

  f32x4 acc[4][4];
  #pragma unroll
  for (int i=0;i<4;++i)
    #pragma unroll
    for (int j=0;j<4;++j) acc[i][j] = (f32x4){0.f,0.f,0.f,0.f};

  for (int k0 = 0; k0 < LAT; k0 += 32) {
    gload16(Asrc0, AsD0); gload16(Asrc1, AsD1);
    gload16(Bsrc0, BsD0); gload16(Bsrc1, BsD1);
    Asrc0 += 64; Asrc1 += 64; Bsrc0 += 64; Bsrc1 += 64;
    __syncthreads();
    short8 a[4], b[4];
    #pragma unroll
    for (int i=0;i<4;++i) a[i] = *(short8*)((char*)As + (wm + i*16 + lr)*64 + lg*16);
    #pragma unroll
    for (int i=0;i<4;++i) b[i] = *(short8*)((char*)Bs + (wn + i*16 + lr)*64 + lg*16);
    #pragma unroll
    for (int i=0;i<4;++i)
      #pragma unroll
      for (int j=0;j<4;++j)
        acc[i][j] = __builtin_amdgcn_mfma_f32_16x16x32_bf16(a[i], b[j], acc[i][j], 0,0,0);
    __syncthreads();
  }

  float psum[4][4];
  #pragma unroll
  for (int i=0;i<4;++i)
    #pragma unroll
    for (int r=0;r<4;++r) psum[i][r] = 0.f;

  const int collocal0 = blockIdx.x * 128 + wn;
  #pragma unroll
  for (int i=0;i<4;++i)
    #pragma unroll
    for (int j=0;j<4;++j)
      #pragma unroll
      for (int r=0;r<4;++r) {
        float p = __expf(acc[i][j][r]);
        psum[i][r] += p;
        Pc[(size_t)(m0 + wm + i*16 + lg*4 + r)*chunk + collocal0 + j*16 + lr] = f2bf(p);
      }
  #pragma unroll
  for (int i=0;i<4;++i)
    #pragma unroll
    for (int r=0;r<4;++r) {
      float v = psum[i][r];
      v += __shfl_xor(v, 1, 16); v += __shfl_xor(v, 2, 16);
      v += __shfl_xor(v, 4, 16); v += __shfl_xor(v, 8, 16);
      if (lr == 0) lsum[wm + i*16 + lg*4 + r][w & 1] = v;
    }
  __syncthreads();
  if (t < 128) {
    int jsl = (cbase >> 7) + blockIdx.x;
    lpart[(size_t)jsl*ENC_B + m0 + t] = lsum[t][0] + lsum[t][1];
  }
}

// ---------------- kernel 6: Z-chunk GEMM, pure-write bf16 slices --------------------
// zb[slice][512 d][8192 rows] bf16 = kvT[:, krange] @ Pc-slice (no RMW for nc=4).
// Tile 128 rows x 64 d, BK=64, XOR-swizzled LDS (stride-128B rows).
// grid dim3(ENC_B/128=64, LAT/64=8, 2 splitK), 256 thr.
__global__ __launch_bounds__(256, 4) void z_gemm_kernel(const short* __restrict__ kvT,
                                                        const short* __restrict__ Pc,
                                                        short* __restrict__ zb,
                                                        int cbase, int chunk,
                                                        int sliceBase, int first){
  __shared__ __align__(16) short As[64*64];      // 8 KB  [d][k] swizzled
  __shared__ __align__(16) short Bs[128*64];     // 16 KB [row][k] swizzled
  const int t = threadIdx.x;
  const int lane = t & 63, w = t >> 6;
  const int lr = lane & 15, lg = lane >> 4;
  const int n0 = blockIdx.x * 128;               // q-rows
  const int m0 = blockIdx.y * 64;                // d
  const int s  = blockIdx.z;
  const int sl = sliceBase + s;
  const int klocal0 = s * (chunk >> 1);

  // staging sources: op covers chunk ca = i*256 + w*64 + lane; row = ca>>3;
  // within-row 16B chunk kc = lane&7, fetched from global chunk kc ^ (row&7).
  const short* Asrc[2];
  #pragma unroll
  for (int i=0;i<2;++i){
    int ca = i*256 + w*64 + lane;
    int row = ca >> 3;
    int kcs = (lane & 7) ^ (row & 7);
    Asrc[i] = kvT + (size_t)(m0 + row)*NFED + cbase + klocal0 + kcs*8;
  }
  const short* Bsrc[4];
  #pragma unroll
  for (int i=0;i<4;++i){
    int ca = i*256 + w*64 + lane;
    int row = ca >> 3;
    int kcs = (lane & 7) ^ (row & 7);
    Bsrc[i] = Pc + (size_t)(n0 + row)*chunk + klocal0 + kcs*8;
  }

  f32x4 acc[2][4];                               // [ri][dj]
  #pragma unroll
  for (int i=0;i<2;++i)
    #pragma unroll
    for (int j=0;j<4;++j) acc[i][j] = (f32x4){0.f,0.f,0.f,0.f};

  const int ksteps = chunk >> 7;                 // (chunk/2)/64
  for (int ks = 0; ks < ksteps; ++ks) {
    #pragma unroll
    for (int i=0;i<2;++i){
      gload16(Asrc[i], (char*)As + i*4096 + w*1024);
      Asrc[i] += 64;
    }
    #pragma unroll
    for (int i=0;i<4;++i){
      gload16(Bsrc[i], (char*)Bs + i*4096 + w*1024);
      Bsrc[i] += 64;
    }
    __syncthreads();                             // drains vmcnt: tiles ready

    #pragma unroll
    for (int kk=0;kk<2;++kk){
      const uint32_t kbyte = kk*64 + lg*16;
      short8 a[4], b[2];
      #pragma unroll
      for (int dj=0;dj<4;++dj){
        int row = dj*16 + lr;
        a[dj] = *(short8*)((char*)As + row*128 + (kbyte ^ ((uint32_t)(row & 7) << 4)));
      }
      #pragma unroll
      for (int ri=0;ri<2;++ri){
        int row = w*32 + ri*16 + lr;
        b[ri] = *(short8*)((char*)Bs + row*128 + (kbyte ^ ((uint32_t)(row & 7) << 4)));
      }
      #pragma unroll
      for (int ri=0;ri<2;++ri)
        #pragma unroll
        for (int dj=0;dj<4;++dj)
          acc[ri][dj] = __builtin_amdgcn_mfma_f32_16x16x32_bf16(a[dj], b[ri], acc[ri][dj], 0,0,0);
    }
    __syncthreads();                             // LDS consumed; safe to restage
  }

  // epilogue: write (or RMW for fallback tiers) bf16 slice
  #pragma unroll
  for (int ri=0;ri<2;++ri)
    #pragma unroll
    for (int dj=0;dj<4;++dj)
      #pragma unroll
      for (int r=0;r<4;++r) {
        int d    = m0 + dj*16 + lg*4 + r;
        int rowq = n0 + w*32 + ri*16 + lr;
        size_t idx = ((size_t)sl*LAT + d)*ENC_B + rowq;
        float v = acc[ri][dj][r];
        if (!first) v += bf2f(zb[idx]);
        zb[idx] = f2bf(v);
      }
}

// ---------------- kernel 7: linv[row] = 1 / sum_j lpart[j][row] ---------------------
__global__ __launch_bounds__(256) void lred_kernel(const float* __restrict__ lpart,
                                                   float* __restrict__ linv){
  const int row = blockIdx.x*256 + threadIdx.x;  // grid 32
  float sum = 0.f;
  for (int j = 0; j < NFED/128; ++j)
    sum += lpart[(size_t)j*ENC_B + row];
  linv[row] = 1.0f / sum;
}

// ---------------- kernel 8: out[row][d] = (sum_sl zb[sl][d][row]) * linv[row] -------
__global__ __launch_bounds__(256) void zcomb_kernel(const short* __restrict__ zb,
                                                    const float* __restrict__ linv,
                                                    float* __restrict__ out){
  __shared__ float tile[64][65];
  const int t = threadIdx.x;
  const int bx = blockIdx.x;                     // row-tile 0..127
  const int by = blockIdx.y;                     // d-tile 0..7
  #pragma unroll
  for (int i=0;i<4;++i){
    int idx = t + i*256;                         // 1024 quads = 64x64
    int dr = idx >> 4, rc = (idx & 15)*4;
    float s0=0.f, s1=0.f, s2=0.f, s3=0.f;
    #pragma unroll
    for (int sl=0; sl<8; ++sl){
      short4_t v = *(const short4_t*)(zb + ((size_t)sl*LAT + by*64 + dr)*ENC_B + bx*64 + rc);
      s0 += bf2f(v[0]); s1 += bf2f(v[1]); s2 += bf2f(v[2]); s3 += bf2f(v[3]);
    }
    tile[dr][rc+0]=s0; tile[dr][rc+1]=s1; tile[dr][rc+2]=s2; tile[dr][rc+3]=s3;
  }
  __syncthreads();
  #pragma unroll
  for (int i=0;i<4;++i){
    int idx = t + i*256;
    int rr = idx >> 4, dc = (idx & 15)*4;
    float li = linv[bx*64 + rr];
    float4 o;
    o.x = tile[dc+0][rr]*li; o.y = tile[dc+1][rr]*li;
    o.z = tile[dc+2][rr]*li; o.w = tile[dc+3][rr]*li;
    *(float4*)(out + (size_t)(bx*64+rr)*LAT + by*64 + dc) = o;
  }
}

extern "C" void kernel_launch(void* const* d_in, const int* in_sizes, int n_in,
                              void* d_out, int out_size, void* d_ws, size_t ws_size,
                              hipStream_t stream) {
  const float* enc = (const float*)d_in[0];   // 8192 x 512
  const float* X   = (const float*)d_in[1];   // 16384 x 1024
  const float* dd  = (const float*)d_in[2];   // 1024 x 512
  float* out = (float*)d_out;                  // 8192 x 512 f32

  // ws layout (bytes):
  //   kv    @ 0          16,777,216
  //   kvT   @ 16,777,216 16,777,216
  //   encb  @ 33,554,432  8,388,608
  //   lpart @ 41,943,040  4,194,304   (ddT overlays, dead before lpart use)
  //   linv  @ 46,137,344     32,768
  //   zb    @ 50,331,648 67,108,864   (8 bf16 slices x 8 MB)
  //   Pc    @117,440,512 chunk*16384
  short* kvb   = (short*)d_ws;
  short* kvT   = (short*)((char*)d_ws + 16777216);
  short* encb  = (short*)((char*)d_ws + 33554432);
  float* lpart = (float*)((char*)d_ws + 41943040);
  short* ddT   = (short*)((char*)d_ws + 41943040);   // prep only
  float* linv  = (float*)((char*)d_ws + 46137344);
  short* zb    = (short*)((char*)d_ws + 50331648);
  short* Pc    = (short*)((char*)d_ws + 117440512);

  // tier: ws >= 184,549,376 (proven present) -> chunk 4096; else smaller chunks
  int chunk;
  if      (ws_size >= (size_t)117440512 + (size_t)4096*ENC_B*2) chunk = 4096;
  else if (ws_size >= (size_t)117440512 + (size_t)2048*ENC_B*2) chunk = 2048;
  else                                                          chunk = 1024;

  ddT_kernel<<<LAT, 256, 0, stream>>>(dd, ddT);
  kv_gemm_kernel<<<(NFED/128)*(LAT/128), 256, 0, stream>>>(X, ddT, kvb);
  kvT_kernel<<<(NFED/64)*(LAT/64), 256, 0, stream>>>(kvb, kvT);
  encb_kernel<<<ENC_B*LAT/(256*8), 256, 0, stream>>>(enc, encb);

  const int nc = NFED / chunk;
  for (int c = 0; c < nc; ++c) {
    s_gemm_kernel<<<dim3(chunk/128, ENC_B/128), 256, 0, stream>>>(
        encb, kvb, Pc, lpart, c*chunk, chunk);
    // slices: (c mod 4)*2 + splitK-half; pure write for c<4 (nc=4 => never RMW)
    z_gemm_kernel<<<dim3(ENC_B/128, LAT/64, 2), 256, 0, stream>>>(
        kvT, Pc, zb, c*chunk, chunk, (c & 3)*2, (c < 4) ? 1 : 0);
  }
  lred_kernel<<<ENC_B/256, 256, 0, stream>>>(lpart, linv);
  zcomb_kernel<<<dim3(ENC_B/64, LAT/64), 256, 0, stream>>>(zb, linv, out);
}